// Round 7
// baseline (89.875 us; speedup 1.0000x reference)
//
#include <hip/hip_runtime.h>

// MVDR 5x5 complex solve, round 7: persistent blocks + N-prefetch into
// REGISTERS (T14 global->reg->LDS) so LDS stays 12.8KB (12 blocks/CU,
// 3 waves/SIMD) while the N-wait is covered by a full iteration of work.
// Rounds 5/6 were latency-bound on the per-block exposed N-wait; round 4
// showed LDS-double-buffer prefetch costs too much occupancy. This keeps
// both. vmcnt ledger (verified): loop-top outstanding = N13+store1 ->
// vmcnt(1); mid = store1+S13+X5+N13=32 -> vmcnt(13) retires store+S+X.
// Preheader issues a dummy VMEM op so first-iter count matches backedge.
// All tail loads are address-CLAMPED (never exec-skipped) so VMEM counts
// are exact. Math = round 6 (unpivoted GJ, pk-friendly cfma).

constexpr int MD = 5;
constexpr int TT = 600, FF = 513;
constexpr int TOTAL = 2 * TT * FF;                 // 615600
constexpr int CELLS = 64;
constexpr int NCH   = (TOTAL + CELLS - 1) / CELLS; // 9619 (tail = 48 cells)
constexpr int MATB  = CELLS * 200;                 // 12800 B
constexpr int GRID  = 3072;                        // 12 blocks/CU * 256 CU
constexpr long long CORRB = (long long)TOTAL * 200;

typedef const __attribute__((address_space(1))) void* gas_t;
typedef __attribute__((address_space(3))) void* las_t;

__device__ __forceinline__ void load_lds16(const void* g, void* l) {
    __builtin_amdgcn_global_load_lds((gas_t)g, (las_t)l, 16, 0, 0);
}

#define WAITV(n) do { asm volatile("s_waitcnt vmcnt(" #n ")" ::: "memory"); \
                      __builtin_amdgcn_sched_barrier(0); } while (0)
#define WAITLGKM0 do { asm volatile("s_waitcnt lgkmcnt(0)" ::: "memory"); \
                       __builtin_amdgcn_sched_barrier(0); } while (0)
#define SCHED_FENCE() __builtin_amdgcn_sched_barrier(0)

// acc += a*b (complex)
__device__ __forceinline__ void cfma(float2& acc, float2 a, float2 b) {
    acc.x = __builtin_fmaf(a.x, b.x, acc.x);
    acc.y = __builtin_fmaf(a.x, b.y, acc.y);
    acc.x = __builtin_fmaf(-a.y, b.y, acc.x);
    acc.y = __builtin_fmaf(a.y, b.x, acc.y);
}
// acc -= a*b (complex)
__device__ __forceinline__ void cfms(float2& acc, float2 a, float2 b) {
    acc.x = __builtin_fmaf(-a.x, b.x, acc.x);
    acc.y = __builtin_fmaf(-a.x, b.y, acc.y);
    acc.x = __builtin_fmaf(a.y, b.y, acc.x);
    acc.y = __builtin_fmaf(-a.y, b.x, acc.y);
}
__device__ __forceinline__ float2 cmul(float2 a, float2 b) {
    return make_float2(a.x * b.x - a.y * b.y, a.x * b.y + a.y * b.x);
}

__global__ __launch_bounds__(64, 3) void mvdr_kernel(
    const float* __restrict__ spec,    // (B,T,F,M,2)   40B/cell
    const float* __restrict__ corrS,   // (B,T,F,M,M,2) 200B/cell
    const float* __restrict__ corrN,   // (B,T,F,M,M,2) 200B/cell
    float* __restrict__ out)           // (B,F,T,2)
{
    __shared__ __align__(16) unsigned char buf[MATB];
    const int tid = threadIdx.x;
    const char* gN = (const char*)corrN;
    const char* gS = (const char*)corrS;

    // ---- prologue: prefetch N[first chunk] into regs (coalesced) ----
    float4 nxt4[12];
    float2 nxt2;
    {
        const long long nb = (long long)blockIdx.x * MATB;   // < NCH*MATB, full
#pragma unroll
        for (int i = 0; i < 12; ++i)
            nxt4[i] = *reinterpret_cast<const float4*>(gN + nb + i * 1024 + tid * 16);
        nxt2 = *reinterpret_cast<const float2*>(gN + nb + 12288 + tid * 8);
    }
    SCHED_FENCE();
    // dummy VMEM op: loop-top outstanding = 14 on entry path too
    {
        float d = *(volatile const float*)gN;
        asm volatile("" :: "v"(d));
    }
    SCHED_FENCE();

    for (int c = blockIdx.x; c < NCH; c += GRID) {
        // ---- N-regs ready (13 oldest retired); dummy/store may fly ----
        WAITV(1);

        // ---- ds_write staged N into buf (linear copy of the window) ----
#pragma unroll
        for (int i = 0; i < 12; ++i)
            *reinterpret_cast<float4*>(buf + i * 1024 + tid * 16) = nxt4[i];
        *reinterpret_cast<float2*>(buf + 12288 + tid * 8) = nxt2;

        // ---- per-cell read N -> A regs (in-order DS => sees writes) ----
        const float2* lm = reinterpret_cast<const float2*>(buf + tid * 200);
        float2 A[MD][MD];
#pragma unroll
        for (int i = 0; i < MD; ++i)
#pragma unroll
            for (int j = 0; j < MD; ++j) A[i][j] = lm[i * MD + j];
        WAITLGKM0;   // A in regs; buf free for S; nxt regs free for reload

        const long long cb = (long long)c * MATB;
        const long long remL = CORRB - cb;
        const int remS = (int)(remL < (long long)MATB ? remL : (long long)MATB);

        // ---- issue S[cur] -> buf (13 gll; i=12 is half-wave; addr clamped) ----
#pragma unroll
        for (int i = 0; i < 13; ++i) {
            int off = i * 1024 + tid * 16;
            if (off + 16 <= MATB) {          // uniform-true for i<12, lanes<32 for i=12
                int goff = off <= remS - 16 ? off : remS - 16;
                load_lds16(gS + cb + goff, buf + off);
            }
        }
        SCHED_FENCE();

        // ---- issue X[cur] -> regs (5 loads, clamped cell) ----
        const int myCell = c * CELLS + tid;
        float2 xv[MD];
        {
            int cc = myCell < TOTAL ? myCell : TOTAL - 1;
            const float2* px = (const float2*)spec + (size_t)cc * MD;
#pragma unroll
            for (int m = 0; m < MD; ++m) xv[m] = px[m];
        }
        SCHED_FENCE();

        // ---- issue N[c+GRID] -> regs (13 loads, clamped; stays in flight) ----
        const bool hasNext = (c + GRID) < NCH;
        if (hasNext) {
            const long long nb = (long long)(c + GRID) * MATB;
#pragma unroll
            for (int i = 0; i < 12; ++i) {
                long long off = nb + i * 1024 + tid * 16;
                if (off > CORRB - 16) off = CORRB - 16;
                nxt4[i] = *reinterpret_cast<const float4*>(gN + off);
            }
            long long off2 = nb + 12288 + tid * 8;
            if (off2 > CORRB - 8) off2 = CORRB - 8;
            nxt2 = *reinterpret_cast<const float2*>(gN + off2);
        }
        SCHED_FENCE();

        // ---- invert A in place (unpivoted GJ; covers S flight) ----
#pragma unroll
        for (int i = 0; i < MD; ++i) { A[i][i].x += 1e-7f; A[i][i].y += 1e-7f; }
#pragma unroll
        for (int k = 0; k < MD; ++k) {
            float2 p = A[k][k];
            float d  = 1.0f / (p.x * p.x + p.y * p.y);
            float2 ip = make_float2(p.x * d, -p.y * d);
            A[k][k] = ip;
#pragma unroll
            for (int cc = 0; cc < MD; ++cc) {
                if (cc == k) continue;
                A[k][cc] = cmul(A[k][cc], ip);
            }
#pragma unroll
            for (int i2 = 0; i2 < MD; ++i2) {
                if (i2 == k) continue;
                float2 fz = A[i2][k];
#pragma unroll
                for (int cc = 0; cc < MD; ++cc) {
                    if (cc == k) continue;
                    cfms(A[i2][cc], fz, A[k][cc]);
                }
                float2 tt = cmul(fz, ip);
                A[i2][k] = make_float2(-tt.x, -tt.y);
            }
        }

        // ---- S+X landed; next-N (13) stays in flight across iteration ----
        if (hasNext) { WAITV(13); } else { WAITV(0); }

        // ---- consume S: trace(N^-1 S) (2 chains), a1 = N^-1 S[:,0] ----
        float2 tr0 = make_float2(0.f, 0.f), tr1 = make_float2(0.f, 0.f);
        float2 a1[MD] = {};
#pragma unroll
        for (int j = 0; j < MD; ++j) {
#pragma unroll
            for (int i = 0; i < MD; ++i) {
                float2 sv = lm[j * MD + i];
                if (((j + i) & 1) == 0) cfma(tr0, A[i][j], sv);
                else                    cfma(tr1, A[i][j], sv);
                if (i == 0) {
#pragma unroll
                    for (int m = 0; m < MD; ++m) cfma(a1[m], A[m][j], sv);
                }
            }
        }
        const float eps = 1.1920929e-07f;
        float2 tr = make_float2(tr0.x + tr1.x + eps, tr0.y + tr1.y + eps);

        // z = sum_m conj(a1[m]) * x[m]
        float2 z = make_float2(0.f, 0.f);
#pragma unroll
        for (int m = 0; m < MD; ++m) {
            z.x = __builtin_fmaf(a1[m].x, xv[m].x, z.x);
            z.y = __builtin_fmaf(a1[m].x, xv[m].y, z.y);
            z.x = __builtin_fmaf(a1[m].y, xv[m].y, z.x);
            z.y = __builtin_fmaf(-a1[m].y, xv[m].x, z.y);
        }

        // S_hat = z / conj(tr) = z * tr / |tr|^2
        float inv2 = 1.0f / (tr.x * tr.x + tr.y * tr.y);
        float shr = (z.x * tr.x - z.y * tr.y) * inv2;
        float shi = (z.x * tr.y + z.y * tr.x) * inv2;

        // ---- store (B,F,T,2) ----
        if (myCell < TOTAL) {
            int f  = myCell % FF;
            int bt = myCell / FF;
            int t  = bt % TT;
            int b  = bt / TT;
            float2* po = reinterpret_cast<float2*>(out);
            po[((size_t)b * FF + f) * TT + t] = make_float2(shr, shi);
        }
    }
}

extern "C" void kernel_launch(void* const* d_in, const int* in_sizes, int n_in,
                              void* d_out, int out_size, void* d_ws, size_t ws_size,
                              hipStream_t stream) {
    const float* spec  = (const float*)d_in[0];
    const float* corrS = (const float*)d_in[1];
    const float* corrN = (const float*)d_in[2];
    float* out = (float*)d_out;

    mvdr_kernel<<<GRID, CELLS, 0, stream>>>(spec, corrS, corrN, out);
}

// Round 8
// 79.668 us; speedup vs baseline: 1.1281x; 1.1281x over previous
//
#include <hip/hip_runtime.h>

// MVDR 5x5 complex solve, round 8: round-7 pipeline (persistent blocks,
// next-N prefetched into REGISTERS, one 12.8KB LDS buffer time-multiplexed
// N->S, zero barriers, counted vmcnt) with the SPILL FIXED:
//  - amdgpu_waves_per_eu(3,3): occupancy is LDS-capped at 3 waves/SIMD
//    anyway; pinning stops the backend from spilling to chase 6 waves/EU
//    (round 7: VGPR 84, WRITE_SIZE 127MB of scratch traffic).
//  - prefetch in 12 NAMED float4 vars + 1 float2 (no array).
//  - prologue dummy op uses a lane-varying address so it is guaranteed
//    VMEM (vmcnt), keeping the ledger exact.
// vmcnt ledger: loop-top = N13 + store1 -> vmcnt(1) retires all N;
// mid-loop = store1 + S13 + X + N13 -> vmcnt(13) retires store+S+X,
// N13 stays in flight across the whole next iteration. Tail loads are
// address-clamped (never exec-skipped) so counts are exact.
// Math = round 6 (unpivoted GJ, pk-friendly cfma).

constexpr int MD = 5;
constexpr int TT = 600, FF = 513;
constexpr int TOTAL = 2 * TT * FF;                 // 615600
constexpr int CELLS = 64;
constexpr int NCH   = (TOTAL + CELLS - 1) / CELLS; // 9619 (tail = 48 cells)
constexpr int MATB  = CELLS * 200;                 // 12800 B
constexpr int GRID  = 3072;                        // 12 blocks/CU * 256 CU
constexpr long long CORRB = (long long)TOTAL * 200;

typedef const __attribute__((address_space(1))) void* gas_t;
typedef __attribute__((address_space(3))) void* las_t;

__device__ __forceinline__ void load_lds16(const void* g, void* l) {
    __builtin_amdgcn_global_load_lds((gas_t)g, (las_t)l, 16, 0, 0);
}

#define WAITV(n) do { asm volatile("s_waitcnt vmcnt(" #n ")" ::: "memory"); \
                      __builtin_amdgcn_sched_barrier(0); } while (0)
#define WAITLGKM0 do { asm volatile("s_waitcnt lgkmcnt(0)" ::: "memory"); \
                       __builtin_amdgcn_sched_barrier(0); } while (0)
#define SCHED_FENCE() __builtin_amdgcn_sched_barrier(0)

#define FOR12(OP) OP(0) OP(1) OP(2) OP(3) OP(4) OP(5) \
                  OP(6) OP(7) OP(8) OP(9) OP(10) OP(11)

// acc += a*b (complex)
__device__ __forceinline__ void cfma(float2& acc, float2 a, float2 b) {
    acc.x = __builtin_fmaf(a.x, b.x, acc.x);
    acc.y = __builtin_fmaf(a.x, b.y, acc.y);
    acc.x = __builtin_fmaf(-a.y, b.y, acc.x);
    acc.y = __builtin_fmaf(a.y, b.x, acc.y);
}
// acc -= a*b (complex)
__device__ __forceinline__ void cfms(float2& acc, float2 a, float2 b) {
    acc.x = __builtin_fmaf(-a.x, b.x, acc.x);
    acc.y = __builtin_fmaf(-a.x, b.y, acc.y);
    acc.x = __builtin_fmaf(a.y, b.y, acc.x);
    acc.y = __builtin_fmaf(-a.y, b.x, acc.y);
}
__device__ __forceinline__ float2 cmul(float2 a, float2 b) {
    return make_float2(a.x * b.x - a.y * b.y, a.x * b.y + a.y * b.x);
}

__global__ void __launch_bounds__(64)
__attribute__((amdgpu_waves_per_eu(3, 3)))
mvdr_kernel(
    const float* __restrict__ spec,    // (B,T,F,M,2)   40B/cell
    const float* __restrict__ corrS,   // (B,T,F,M,M,2) 200B/cell
    const float* __restrict__ corrN,   // (B,T,F,M,M,2) 200B/cell
    float* __restrict__ out)           // (B,F,T,2)
{
    __shared__ __align__(16) unsigned char buf[MATB];
    const int tid = threadIdx.x;
    const char* gN = (const char*)corrN;
    const char* gS = (const char*)corrS;

    // ---- prologue: prefetch N[first chunk] into named regs (coalesced) ----
    float4 n0, n1, n2, n3, n4, n5, n6, n7, n8, n9, n10, n11;
    float2 nc;
    {
        const long long nb = (long long)blockIdx.x * MATB;   // full chunk
#define LDP(i) n##i = *reinterpret_cast<const float4*>(gN + nb + i * 1024 + tid * 16);
        FOR12(LDP)
#undef LDP
        nc = *reinterpret_cast<const float2*>(gN + nb + 12288 + tid * 8);
    }
    SCHED_FENCE();
    // dummy VMEM op (lane-varying addr => guaranteed vector load):
    // loop-top outstanding = 14 on the entry path too.
    {
        float d = *(volatile const float*)(gN + ((tid & 1) << 2));
        asm volatile("" :: "v"(d));
    }
    SCHED_FENCE();

    for (int c = blockIdx.x; c < NCH; c += GRID) {
        // ---- N-regs ready (13 oldest retired); dummy/store may fly ----
        WAITV(1);

        // ---- ds_write staged N into buf (linear window copy) ----
#define STP(i) *reinterpret_cast<float4*>(buf + i * 1024 + tid * 16) = n##i;
        FOR12(STP)
#undef STP
        *reinterpret_cast<float2*>(buf + 12288 + tid * 8) = nc;

        // ---- per-cell read N -> A regs (DS pipe in-order per wave) ----
        const float2* lm = reinterpret_cast<const float2*>(buf + tid * 200);
        float2 A[MD][MD];
#pragma unroll
        for (int i = 0; i < MD; ++i)
#pragma unroll
            for (int j = 0; j < MD; ++j) A[i][j] = lm[i * MD + j];
        WAITLGKM0;   // A in regs; buf free for S; n* regs free for reload

        const long long cb = (long long)c * MATB;
        const long long remL = CORRB - cb;
        const int remS = (int)(remL < (long long)MATB ? remL : (long long)MATB);

        // ---- issue S[cur] -> buf (13 gll; i=12 half-wave; addr clamped) ----
#pragma unroll
        for (int i = 0; i < 13; ++i) {
            int off = i * 1024 + tid * 16;
            if (off + 16 <= MATB) {      // uniform-true i<12; lanes<32 for i=12
                int goff = off <= remS - 16 ? off : remS - 16;
                load_lds16(gS + cb + goff, buf + off);
            }
        }
        SCHED_FENCE();

        // ---- issue X[cur] -> regs (clamped cell) ----
        const int myCell = c * CELLS + tid;
        float2 xv[MD];
        {
            int cc = myCell < TOTAL ? myCell : TOTAL - 1;
            const float2* px = (const float2*)spec + (size_t)cc * MD;
#pragma unroll
            for (int m = 0; m < MD; ++m) xv[m] = px[m];
        }
        SCHED_FENCE();

        // ---- issue N[c+GRID] -> regs (13 loads, clamped; stay in flight) ----
        const bool hasNext = (c + GRID) < NCH;
        if (hasNext) {
            const long long nb = (long long)(c + GRID) * MATB;
#define LDN(i) { long long o = nb + i * 1024 + tid * 16;                     \
                 if (o > CORRB - 16) o = CORRB - 16;                         \
                 n##i = *reinterpret_cast<const float4*>(gN + o); }
            FOR12(LDN)
#undef LDN
            long long o2 = nb + 12288 + tid * 8;
            if (o2 > CORRB - 8) o2 = CORRB - 8;
            nc = *reinterpret_cast<const float2*>(gN + o2);
        }
        SCHED_FENCE();

        // ---- invert A in place (unpivoted GJ; covers S flight) ----
#pragma unroll
        for (int i = 0; i < MD; ++i) { A[i][i].x += 1e-7f; A[i][i].y += 1e-7f; }
#pragma unroll
        for (int k = 0; k < MD; ++k) {
            float2 p = A[k][k];
            float d  = 1.0f / (p.x * p.x + p.y * p.y);
            float2 ip = make_float2(p.x * d, -p.y * d);
            A[k][k] = ip;
#pragma unroll
            for (int cc = 0; cc < MD; ++cc) {
                if (cc == k) continue;
                A[k][cc] = cmul(A[k][cc], ip);
            }
#pragma unroll
            for (int i2 = 0; i2 < MD; ++i2) {
                if (i2 == k) continue;
                float2 fz = A[i2][k];
#pragma unroll
                for (int cc = 0; cc < MD; ++cc) {
                    if (cc == k) continue;
                    cfms(A[i2][cc], fz, A[k][cc]);
                }
                float2 tt = cmul(fz, ip);
                A[i2][k] = make_float2(-tt.x, -tt.y);
            }
        }

        // ---- S+X landed; next-N (13) stays in flight across iteration ----
        if (hasNext) { WAITV(13); } else { WAITV(0); }

        // ---- consume S: trace(N^-1 S) (2 chains), a1 = N^-1 S[:,0] ----
        float2 tr0 = make_float2(0.f, 0.f), tr1 = make_float2(0.f, 0.f);
        float2 a1[MD] = {};
#pragma unroll
        for (int j = 0; j < MD; ++j) {
#pragma unroll
            for (int i = 0; i < MD; ++i) {
                float2 sv = lm[j * MD + i];
                if (((j + i) & 1) == 0) cfma(tr0, A[i][j], sv);
                else                    cfma(tr1, A[i][j], sv);
                if (i == 0) {
#pragma unroll
                    for (int m = 0; m < MD; ++m) cfma(a1[m], A[m][j], sv);
                }
            }
        }
        const float eps = 1.1920929e-07f;
        float2 tr = make_float2(tr0.x + tr1.x + eps, tr0.y + tr1.y + eps);

        // z = sum_m conj(a1[m]) * x[m]
        float2 z = make_float2(0.f, 0.f);
#pragma unroll
        for (int m = 0; m < MD; ++m) {
            z.x = __builtin_fmaf(a1[m].x, xv[m].x, z.x);
            z.y = __builtin_fmaf(a1[m].x, xv[m].y, z.y);
            z.x = __builtin_fmaf(a1[m].y, xv[m].y, z.x);
            z.y = __builtin_fmaf(-a1[m].y, xv[m].x, z.y);
        }

        // S_hat = z / conj(tr) = z * tr / |tr|^2
        float inv2 = 1.0f / (tr.x * tr.x + tr.y * tr.y);
        float shr = (z.x * tr.x - z.y * tr.y) * inv2;
        float shi = (z.x * tr.y + z.y * tr.x) * inv2;

        // ---- store (B,F,T,2) ----
        if (myCell < TOTAL) {
            int f  = myCell % FF;
            int bt = myCell / FF;
            int t  = bt % TT;
            int b  = bt / TT;
            float2* po = reinterpret_cast<float2*>(out);
            po[((size_t)b * FF + f) * TT + t] = make_float2(shr, shi);
        }
    }
}

extern "C" void kernel_launch(void* const* d_in, const int* in_sizes, int n_in,
                              void* d_out, int out_size, void* d_ws, size_t ws_size,
                              hipStream_t stream) {
    const float* spec  = (const float*)d_in[0];
    const float* corrS = (const float*)d_in[1];
    const float* corrN = (const float*)d_in[2];
    float* out = (float*)d_out;

    mvdr_kernel<<<GRID, CELLS, 0, stream>>>(spec, corrS, corrN, out);
}

// Round 9
// 48.257 us; speedup vs baseline: 1.8624x; 1.6509x over previous
//
#include <hip/hip_runtime.h>

// MVDR 5x5 complex solve, round 9: round-6 structure (one-shot 1-wave
// blocks, single LDS buffer time-multiplexed N->S, zero barriers, counted
// vmcnt, unpivoted GJ) with a SMALLER chunk: CELLS=48 -> 9600B LDS/wave ->
// 16 blocks/CU = 4 waves/SIMD (was 3). Rounds 7/8 proved the backend
// refuses >84 VGPRs (spills cross-iteration prefetch), so occupancy — not
// pipelining — is the available latency lever. 615600 = 48*12825 exactly:
// NO tail path. Lanes 48-63 stage (full 64-lane coalescing) and compute a
// clamped duplicate of cell 47; only lanes <48 store.
// vmcnt ledger: N=10 gll, X=exactly 3 VMEM (2xfloat4+1xfloat2, 8B-aligned;
// dwordx4 is dword-align-safe) -> WAITV(3) retires all N even if the
// compiler reorders/merges; WAITV(0) before consume.

constexpr int MD = 5;
constexpr int TT = 600, FF = 513;
constexpr int TOTAL = 2 * TT * FF;                 // 615600
constexpr int CELLS = 48;
constexpr int NCH   = TOTAL / CELLS;               // 12825, exact
constexpr int MATB  = CELLS * 200;                 // 9600 B

typedef const __attribute__((address_space(1))) void* gas_t;
typedef __attribute__((address_space(3))) void* las_t;

__device__ __forceinline__ void load_lds16(const void* g, void* l) {
    __builtin_amdgcn_global_load_lds((gas_t)g, (las_t)l, 16, 0, 0);
}

#define WAITV(n) do { asm volatile("s_waitcnt vmcnt(" #n ")" ::: "memory"); \
                      __builtin_amdgcn_sched_barrier(0); } while (0)
#define WAITLGKM0 do { asm volatile("s_waitcnt lgkmcnt(0)" ::: "memory"); \
                       __builtin_amdgcn_sched_barrier(0); } while (0)
#define SCHED_FENCE() __builtin_amdgcn_sched_barrier(0)

// acc += a*b (complex)
__device__ __forceinline__ void cfma(float2& acc, float2 a, float2 b) {
    acc.x = __builtin_fmaf(a.x, b.x, acc.x);
    acc.y = __builtin_fmaf(a.x, b.y, acc.y);
    acc.x = __builtin_fmaf(-a.y, b.y, acc.x);
    acc.y = __builtin_fmaf(a.y, b.x, acc.y);
}
// acc -= a*b (complex)
__device__ __forceinline__ void cfms(float2& acc, float2 a, float2 b) {
    acc.x = __builtin_fmaf(-a.x, b.x, acc.x);
    acc.y = __builtin_fmaf(-a.x, b.y, acc.y);
    acc.x = __builtin_fmaf(a.y, b.y, acc.x);
    acc.y = __builtin_fmaf(-a.y, b.x, acc.y);
}
__device__ __forceinline__ float2 cmul(float2 a, float2 b) {
    return make_float2(a.x * b.x - a.y * b.y, a.x * b.y + a.y * b.x);
}

__global__ __launch_bounds__(64) void mvdr_kernel(
    const float* __restrict__ spec,    // (B,T,F,M,2)   40B/cell
    const float* __restrict__ corrS,   // (B,T,F,M,M,2) 200B/cell
    const float* __restrict__ corrN,   // (B,T,F,M,M,2) 200B/cell
    float* __restrict__ out)           // (B,F,T,2)
{
    __shared__ __align__(16) unsigned char buf[MATB];
    const int tid = threadIdx.x;
    const int c   = blockIdx.x;
    const int ct  = tid < CELLS ? tid : CELLS - 1;   // clamped compute cell
    const size_t byteBase = (size_t)c * MATB;

    // ---- 1. issue Phi_N staging: 10 gll (9 full + lanes 0-23) ----
    {
        const char* gN = (const char*)corrN + byteBase;
#pragma unroll
        for (int i = 0; i < 10; ++i) {
            int off = i * 1024 + tid * 16;
            if (off + 16 <= MATB) load_lds16(gN + off, (char*)buf + off);
        }
    }
    SCHED_FENCE();

    // ---- 2. spec -> regs: EXACTLY 3 VMEM instrs (2x dwordx4 + 1x dwordx2) ----
    float4 xa, xb; float2 xc;
    {
        const char* px = (const char*)spec + (size_t)(c * CELLS + ct) * 40;
        xa = *reinterpret_cast<const float4*>(px);
        xb = *reinterpret_cast<const float4*>(px + 16);
        xc = *reinterpret_cast<const float2*>(px + 32);
    }
    SCHED_FENCE();

    // ---- 3. N ready (10 oldest retired); X may stay in flight ----
    WAITV(3);
    float2 A[MD][MD];
    const float2* lm = reinterpret_cast<const float2*>(buf + ct * 200);
#pragma unroll
    for (int i = 0; i < MD; ++i)
#pragma unroll
        for (int j = 0; j < MD; ++j) A[i][j] = lm[i * MD + j];
    WAITLGKM0;   // N fully in regs before S overwrites the buffer

    // ---- 4. issue Phi_S staging into the SAME buffer ----
    {
        const char* gS = (const char*)corrS + byteBase;
#pragma unroll
        for (int i = 0; i < 10; ++i) {
            int off = i * 1024 + tid * 16;
            if (off + 16 <= MATB) load_lds16(gS + off, (char*)buf + off);
        }
    }
    SCHED_FENCE();

    // ---- 5. unpivoted in-place Gauss-Jordan inverse (covers S flight) ----
#pragma unroll
    for (int i = 0; i < MD; ++i) { A[i][i].x += 1e-7f; A[i][i].y += 1e-7f; }
#pragma unroll
    for (int k = 0; k < MD; ++k) {
        float2 p = A[k][k];
        float d  = 1.0f / (p.x * p.x + p.y * p.y);
        float2 ip = make_float2(p.x * d, -p.y * d);
        A[k][k] = ip;
#pragma unroll
        for (int cc = 0; cc < MD; ++cc) {
            if (cc == k) continue;
            A[k][cc] = cmul(A[k][cc], ip);
        }
#pragma unroll
        for (int i2 = 0; i2 < MD; ++i2) {
            if (i2 == k) continue;
            float2 fz = A[i2][k];
#pragma unroll
            for (int cc = 0; cc < MD; ++cc) {
                if (cc == k) continue;
                cfms(A[i2][cc], fz, A[k][cc]);
            }
            float2 tt = cmul(fz, ip);
            A[i2][k] = make_float2(-tt.x, -tt.y);
        }
    }

    // ---- 6. S staged and X landed ----
    WAITV(0);

    // ---- 7. stream Phi_S: trace(N^-1 S) (2 chains), a1 = N^-1 S[:,0] ----
    float2 tr0 = make_float2(0.f, 0.f), tr1 = make_float2(0.f, 0.f);
    float2 a1[MD] = {};
#pragma unroll
    for (int j = 0; j < MD; ++j) {
#pragma unroll
        for (int i = 0; i < MD; ++i) {
            float2 sv = lm[j * MD + i];
            if (((j + i) & 1) == 0) cfma(tr0, A[i][j], sv);
            else                    cfma(tr1, A[i][j], sv);
            if (i == 0) {
#pragma unroll
                for (int m = 0; m < MD; ++m) cfma(a1[m], A[m][j], sv);
            }
        }
    }
    const float eps = 1.1920929e-07f;
    float2 tr = make_float2(tr0.x + tr1.x + eps, tr0.y + tr1.y + eps);

    // ---- 8. z = sum_m conj(a1[m]) * x[m] ----
    float2 xv[MD];
    xv[0] = make_float2(xa.x, xa.y);
    xv[1] = make_float2(xa.z, xa.w);
    xv[2] = make_float2(xb.x, xb.y);
    xv[3] = make_float2(xb.z, xb.w);
    xv[4] = xc;
    float2 z = make_float2(0.f, 0.f);
#pragma unroll
    for (int m = 0; m < MD; ++m) {
        z.x = __builtin_fmaf(a1[m].x, xv[m].x, z.x);
        z.y = __builtin_fmaf(a1[m].x, xv[m].y, z.y);
        z.x = __builtin_fmaf(a1[m].y, xv[m].y, z.x);
        z.y = __builtin_fmaf(-a1[m].y, xv[m].x, z.y);
    }

    // S_hat = z / conj(tr) = z * tr / |tr|^2
    float inv2 = 1.0f / (tr.x * tr.x + tr.y * tr.y);
    float shr = (z.x * tr.x - z.y * tr.y) * inv2;
    float shi = (z.x * tr.y + z.y * tr.x) * inv2;

    // ---- 9. store (B,F,T,2), lanes < 48 only ----
    if (tid < CELLS) {
        int myCell = c * CELLS + tid;
        int f  = myCell % FF;
        int bt = myCell / FF;
        int t  = bt % TT;
        int b  = bt / TT;
        float2* po = reinterpret_cast<float2*>(out);
        po[((size_t)b * FF + f) * TT + t] = make_float2(shr, shi);
    }
}

extern "C" void kernel_launch(void* const* d_in, const int* in_sizes, int n_in,
                              void* d_out, int out_size, void* d_ws, size_t ws_size,
                              hipStream_t stream) {
    const float* spec  = (const float*)d_in[0];
    const float* corrS = (const float*)d_in[1];
    const float* corrN = (const float*)d_in[2];
    float* out = (float*)d_out;

    mvdr_kernel<<<NCH, 64, 0, stream>>>(spec, corrS, corrN, out);
}

// Round 10
// 48.124 us; speedup vs baseline: 1.8676x; 1.0028x over previous
//
#include <hip/hip_runtime.h>

// MVDR 5x5 complex solve, round 10: round-9 kernel (CELLS=48, 9600B LDS,
// 16 blocks/CU = 4 waves/SIMD, zero barriers, counted vmcnt, unpivoted GJ)
// with the register allocator PINNED: __launch_bounds__(64, 4) declares
// min 4 waves/EU -> VGPR cap 128. Round 9's allocator targeted ~10
// waves/EU (VGPR 52, ~95 live -> scratch spill, WRITE_SIZE 15.8MB vs
// 5.4MB logical). 4 waves/EU is exactly the LDS-capped occupancy, and the
// ~95-reg live set fits under 128, so the allocator can neither spill for
// occupancy nor run out of budget. Everything else identical to round 9.

constexpr int MD = 5;
constexpr int TT = 600, FF = 513;
constexpr int TOTAL = 2 * TT * FF;                 // 615600
constexpr int CELLS = 48;
constexpr int NCH   = TOTAL / CELLS;               // 12825, exact
constexpr int MATB  = CELLS * 200;                 // 9600 B

typedef const __attribute__((address_space(1))) void* gas_t;
typedef __attribute__((address_space(3))) void* las_t;

__device__ __forceinline__ void load_lds16(const void* g, void* l) {
    __builtin_amdgcn_global_load_lds((gas_t)g, (las_t)l, 16, 0, 0);
}

#define WAITV(n) do { asm volatile("s_waitcnt vmcnt(" #n ")" ::: "memory"); \
                      __builtin_amdgcn_sched_barrier(0); } while (0)
#define WAITLGKM0 do { asm volatile("s_waitcnt lgkmcnt(0)" ::: "memory"); \
                       __builtin_amdgcn_sched_barrier(0); } while (0)
#define SCHED_FENCE() __builtin_amdgcn_sched_barrier(0)

// acc += a*b (complex)
__device__ __forceinline__ void cfma(float2& acc, float2 a, float2 b) {
    acc.x = __builtin_fmaf(a.x, b.x, acc.x);
    acc.y = __builtin_fmaf(a.x, b.y, acc.y);
    acc.x = __builtin_fmaf(-a.y, b.y, acc.x);
    acc.y = __builtin_fmaf(a.y, b.x, acc.y);
}
// acc -= a*b (complex)
__device__ __forceinline__ void cfms(float2& acc, float2 a, float2 b) {
    acc.x = __builtin_fmaf(-a.x, b.x, acc.x);
    acc.y = __builtin_fmaf(-a.x, b.y, acc.y);
    acc.x = __builtin_fmaf(a.y, b.y, acc.x);
    acc.y = __builtin_fmaf(-a.y, b.x, acc.y);
}
__device__ __forceinline__ float2 cmul(float2 a, float2 b) {
    return make_float2(a.x * b.x - a.y * b.y, a.x * b.y + a.y * b.x);
}

__global__ __launch_bounds__(64, 4) void mvdr_kernel(
    const float* __restrict__ spec,    // (B,T,F,M,2)   40B/cell
    const float* __restrict__ corrS,   // (B,T,F,M,M,2) 200B/cell
    const float* __restrict__ corrN,   // (B,T,F,M,M,2) 200B/cell
    float* __restrict__ out)           // (B,F,T,2)
{
    __shared__ __align__(16) unsigned char buf[MATB];
    const int tid = threadIdx.x;
    const int c   = blockIdx.x;
    const int ct  = tid < CELLS ? tid : CELLS - 1;   // clamped compute cell
    const size_t byteBase = (size_t)c * MATB;

    // ---- 1. issue Phi_N staging: 10 gll (9 full + lanes 0-23) ----
    {
        const char* gN = (const char*)corrN + byteBase;
#pragma unroll
        for (int i = 0; i < 10; ++i) {
            int off = i * 1024 + tid * 16;
            if (off + 16 <= MATB) load_lds16(gN + off, (char*)buf + off);
        }
    }
    SCHED_FENCE();

    // ---- 2. spec -> regs: EXACTLY 3 VMEM instrs (2x dwordx4 + 1x dwordx2) ----
    float4 xa, xb; float2 xc;
    {
        const char* px = (const char*)spec + (size_t)(c * CELLS + ct) * 40;
        xa = *reinterpret_cast<const float4*>(px);
        xb = *reinterpret_cast<const float4*>(px + 16);
        xc = *reinterpret_cast<const float2*>(px + 32);
    }
    SCHED_FENCE();

    // ---- 3. N ready (10 oldest retired); X may stay in flight ----
    WAITV(3);
    float2 A[MD][MD];
    const float2* lm = reinterpret_cast<const float2*>(buf + ct * 200);
#pragma unroll
    for (int i = 0; i < MD; ++i)
#pragma unroll
        for (int j = 0; j < MD; ++j) A[i][j] = lm[i * MD + j];
    WAITLGKM0;   // N fully in regs before S overwrites the buffer

    // ---- 4. issue Phi_S staging into the SAME buffer ----
    {
        const char* gS = (const char*)corrS + byteBase;
#pragma unroll
        for (int i = 0; i < 10; ++i) {
            int off = i * 1024 + tid * 16;
            if (off + 16 <= MATB) load_lds16(gS + off, (char*)buf + off);
        }
    }
    SCHED_FENCE();

    // ---- 5. unpivoted in-place Gauss-Jordan inverse (covers S flight) ----
#pragma unroll
    for (int i = 0; i < MD; ++i) { A[i][i].x += 1e-7f; A[i][i].y += 1e-7f; }
#pragma unroll
    for (int k = 0; k < MD; ++k) {
        float2 p = A[k][k];
        float d  = 1.0f / (p.x * p.x + p.y * p.y);
        float2 ip = make_float2(p.x * d, -p.y * d);
        A[k][k] = ip;
#pragma unroll
        for (int cc = 0; cc < MD; ++cc) {
            if (cc == k) continue;
            A[k][cc] = cmul(A[k][cc], ip);
        }
#pragma unroll
        for (int i2 = 0; i2 < MD; ++i2) {
            if (i2 == k) continue;
            float2 fz = A[i2][k];
#pragma unroll
            for (int cc = 0; cc < MD; ++cc) {
                if (cc == k) continue;
                cfms(A[i2][cc], fz, A[k][cc]);
            }
            float2 tt = cmul(fz, ip);
            A[i2][k] = make_float2(-tt.x, -tt.y);
        }
    }

    // ---- 6. S staged and X landed ----
    WAITV(0);

    // ---- 7. stream Phi_S: trace(N^-1 S) (2 chains), a1 = N^-1 S[:,0] ----
    float2 tr0 = make_float2(0.f, 0.f), tr1 = make_float2(0.f, 0.f);
    float2 a1[MD] = {};
#pragma unroll
    for (int j = 0; j < MD; ++j) {
#pragma unroll
        for (int i = 0; i < MD; ++i) {
            float2 sv = lm[j * MD + i];
            if (((j + i) & 1) == 0) cfma(tr0, A[i][j], sv);
            else                    cfma(tr1, A[i][j], sv);
            if (i == 0) {
#pragma unroll
                for (int m = 0; m < MD; ++m) cfma(a1[m], A[m][j], sv);
            }
        }
    }
    const float eps = 1.1920929e-07f;
    float2 tr = make_float2(tr0.x + tr1.x + eps, tr0.y + tr1.y + eps);

    // ---- 8. z = sum_m conj(a1[m]) * x[m] ----
    float2 xv[MD];
    xv[0] = make_float2(xa.x, xa.y);
    xv[1] = make_float2(xa.z, xa.w);
    xv[2] = make_float2(xb.x, xb.y);
    xv[3] = make_float2(xb.z, xb.w);
    xv[4] = xc;
    float2 z = make_float2(0.f, 0.f);
#pragma unroll
    for (int m = 0; m < MD; ++m) {
        z.x = __builtin_fmaf(a1[m].x, xv[m].x, z.x);
        z.y = __builtin_fmaf(a1[m].x, xv[m].y, z.y);
        z.x = __builtin_fmaf(a1[m].y, xv[m].y, z.x);
        z.y = __builtin_fmaf(-a1[m].y, xv[m].x, z.y);
    }

    // S_hat = z / conj(tr) = z * tr / |tr|^2
    float inv2 = 1.0f / (tr.x * tr.x + tr.y * tr.y);
    float shr = (z.x * tr.x - z.y * tr.y) * inv2;
    float shi = (z.x * tr.y + z.y * tr.x) * inv2;

    // ---- 9. store (B,F,T,2), lanes < 48 only ----
    if (tid < CELLS) {
        int myCell = c * CELLS + tid;
        int f  = myCell % FF;
        int bt = myCell / FF;
        int t  = bt % TT;
        int b  = bt / TT;
        float2* po = reinterpret_cast<float2*>(out);
        po[((size_t)b * FF + f) * TT + t] = make_float2(shr, shi);
    }
}

extern "C" void kernel_launch(void* const* d_in, const int* in_sizes, int n_in,
                              void* d_out, int out_size, void* d_ws, size_t ws_size,
                              hipStream_t stream) {
    const float* spec  = (const float*)d_in[0];
    const float* corrS = (const float*)d_in[1];
    const float* corrN = (const float*)d_in[2];
    float* out = (float*)d_out;

    mvdr_kernel<<<NCH, 64, 0, stream>>>(spec, corrS, corrN, out);
}

// Round 11
// 46.208 us; speedup vs baseline: 1.9450x; 1.0415x over previous
//
#include <hip/hip_runtime.h>

// MVDR 5x5 complex solve, round 11: round-6 math + DUAL LDS buffers.
// All loads issued at block top: X(3 VMEM) -> N(13 gll) -> S(13 gll);
// vmcnt(13) = N ready (S still in flight), read N -> invert (covers S),
// vmcnt(0) -> consume. Removes round-6's WAR lgkmcnt(0) and late S issue;
// ONE exposed wait per wave. LDS 25.6KB -> 6 blocks/CU (1.5 waves/SIMD);
// one-shot blocks so generation overlap comes from the dispatcher (unlike
// round 4's serial in-wave loop). CELLS=64 shape = the allocator-friendly
// config (VGPR 76, no spill — rounds 8/9/10 proved CELLS=48 + any
// occupancy knob gets sabotaged). Tail block (1/9619) full-drains.

constexpr int MD = 5;
constexpr int TT = 600, FF = 513;
constexpr int TOTAL = 2 * TT * FF;                 // 615600
constexpr int CELLS = 64;
constexpr int NCH   = (TOTAL + CELLS - 1) / CELLS; // 9619 (tail = 48 cells)
constexpr int MATB  = CELLS * 200;                 // 12800 B

typedef const __attribute__((address_space(1))) void* gas_t;
typedef __attribute__((address_space(3))) void* las_t;

__device__ __forceinline__ void load_lds16(const void* g, void* l) {
    __builtin_amdgcn_global_load_lds((gas_t)g, (las_t)l, 16, 0, 0);
}

#define WAITV(n) do { asm volatile("s_waitcnt vmcnt(" #n ")" ::: "memory"); \
                      __builtin_amdgcn_sched_barrier(0); } while (0)
#define SCHED_FENCE() __builtin_amdgcn_sched_barrier(0)

// acc += a*b (complex)
__device__ __forceinline__ void cfma(float2& acc, float2 a, float2 b) {
    acc.x = __builtin_fmaf(a.x, b.x, acc.x);
    acc.y = __builtin_fmaf(a.x, b.y, acc.y);
    acc.x = __builtin_fmaf(-a.y, b.y, acc.x);
    acc.y = __builtin_fmaf(a.y, b.x, acc.y);
}
// acc -= a*b (complex)
__device__ __forceinline__ void cfms(float2& acc, float2 a, float2 b) {
    acc.x = __builtin_fmaf(-a.x, b.x, acc.x);
    acc.y = __builtin_fmaf(-a.x, b.y, acc.y);
    acc.x = __builtin_fmaf(a.y, b.y, acc.x);
    acc.y = __builtin_fmaf(-a.y, b.x, acc.y);
}
__device__ __forceinline__ float2 cmul(float2 a, float2 b) {
    return make_float2(a.x * b.x - a.y * b.y, a.x * b.y + a.y * b.x);
}

__global__ __launch_bounds__(64) void mvdr_kernel(
    const float* __restrict__ spec,    // (B,T,F,M,2)   40B/cell
    const float* __restrict__ corrS,   // (B,T,F,M,M,2) 200B/cell
    const float* __restrict__ corrN,   // (B,T,F,M,M,2) 200B/cell
    float* __restrict__ out)           // (B,F,T,2)
{
    __shared__ __align__(16) unsigned char bufN[MATB];
    __shared__ __align__(16) unsigned char bufS[MATB];
    const int tid    = threadIdx.x;
    const int c      = blockIdx.x;
    const int myCell = c * CELLS + tid;
    const bool full  = (c != NCH - 1);            // wave-uniform
    const size_t byteBase = (size_t)c * MATB;
    const char* gN = (const char*)corrN + byteBase;
    const char* gS = (const char*)corrS + byteBase;

    // ---- 1. issue X -> regs: EXACTLY 3 VMEM (2x dwordx4 + 1x dwordx2) ----
    float4 xa, xb; float2 xc;
    {
        int cc = myCell < TOTAL ? myCell : TOTAL - 1;
        const char* px = (const char*)spec + (size_t)cc * 40;
        xa = *reinterpret_cast<const float4*>(px);
        xb = *reinterpret_cast<const float4*>(px + 16);
        xc = *reinterpret_cast<const float2*>(px + 32);
    }
    SCHED_FENCE();

    // ---- 2. issue N (13 gll) then S (13 gll), both at the top ----
    if (full) {
#pragma unroll
        for (int i = 0; i < 13; ++i) {
            int off = i * 1024 + tid * 16;
            if (off + 16 <= MATB) load_lds16(gN + off, (char*)bufN + off);
        }
        SCHED_FENCE();
#pragma unroll
        for (int i = 0; i < 13; ++i) {
            int off = i * 1024 + tid * 16;
            if (off + 16 <= MATB) load_lds16(gS + off, (char*)bufS + off);
        }
        SCHED_FENCE();
        // outstanding: X3 + N13 + S13; vmcnt(13) retires X+N, S keeps flying
        WAITV(13);
    } else {
        const int rem = TOTAL * 200 - (int)byteBase;   // 9600 on tail
#pragma unroll
        for (int i = 0; i < 13; ++i) {
            int off = i * 1024 + tid * 16;
            if (off + 16 <= rem) load_lds16(gN + off, (char*)bufN + off);
        }
        SCHED_FENCE();
#pragma unroll
        for (int i = 0; i < 13; ++i) {
            int off = i * 1024 + tid * 16;
            if (off + 16 <= rem) load_lds16(gS + off, (char*)bufS + off);
        }
        SCHED_FENCE();
        WAITV(0);    // tail: lazy full drain (1 block, perf-irrelevant)
    }

    // ---- 3. read Phi_N into registers ----
    float2 A[MD][MD];
    const float2* lmN = reinterpret_cast<const float2*>(bufN + tid * 200);
#pragma unroll
    for (int i = 0; i < MD; ++i)
#pragma unroll
        for (int j = 0; j < MD; ++j) A[i][j] = lmN[i * MD + j];

    // ---- 4. unpivoted in-place Gauss-Jordan inverse (covers S flight) ----
#pragma unroll
    for (int i = 0; i < MD; ++i) { A[i][i].x += 1e-7f; A[i][i].y += 1e-7f; }
#pragma unroll
    for (int k = 0; k < MD; ++k) {
        float2 p = A[k][k];
        float d  = 1.0f / (p.x * p.x + p.y * p.y);
        float2 ip = make_float2(p.x * d, -p.y * d);
        A[k][k] = ip;
#pragma unroll
        for (int cc = 0; cc < MD; ++cc) {
            if (cc == k) continue;
            A[k][cc] = cmul(A[k][cc], ip);
        }
#pragma unroll
        for (int i2 = 0; i2 < MD; ++i2) {
            if (i2 == k) continue;
            float2 fz = A[i2][k];
#pragma unroll
            for (int cc = 0; cc < MD; ++cc) {
                if (cc == k) continue;
                cfms(A[i2][cc], fz, A[k][cc]);
            }
            float2 tt = cmul(fz, ip);
            A[i2][k] = make_float2(-tt.x, -tt.y);
        }
    }

    // ---- 5. S landed ----
    WAITV(0);

    // ---- 6. stream Phi_S: trace(N^-1 S) (2 chains), a1 = N^-1 S[:,0] ----
    float2 tr0 = make_float2(0.f, 0.f), tr1 = make_float2(0.f, 0.f);
    float2 a1[MD] = {};
    const float2* lmS = reinterpret_cast<const float2*>(bufS + tid * 200);
#pragma unroll
    for (int j = 0; j < MD; ++j) {
#pragma unroll
        for (int i = 0; i < MD; ++i) {
            float2 sv = lmS[j * MD + i];
            if (((j + i) & 1) == 0) cfma(tr0, A[i][j], sv);
            else                    cfma(tr1, A[i][j], sv);
            if (i == 0) {
#pragma unroll
                for (int m = 0; m < MD; ++m) cfma(a1[m], A[m][j], sv);
            }
        }
    }
    const float eps = 1.1920929e-07f;
    float2 tr = make_float2(tr0.x + tr1.x + eps, tr0.y + tr1.y + eps);

    // ---- 7. z = sum_m conj(a1[m]) * x[m] ----
    float2 xv[MD];
    xv[0] = make_float2(xa.x, xa.y);
    xv[1] = make_float2(xa.z, xa.w);
    xv[2] = make_float2(xb.x, xb.y);
    xv[3] = make_float2(xb.z, xb.w);
    xv[4] = xc;
    float2 z = make_float2(0.f, 0.f);
#pragma unroll
    for (int m = 0; m < MD; ++m) {
        z.x = __builtin_fmaf(a1[m].x, xv[m].x, z.x);
        z.y = __builtin_fmaf(a1[m].x, xv[m].y, z.y);
        z.x = __builtin_fmaf(a1[m].y, xv[m].y, z.x);
        z.y = __builtin_fmaf(-a1[m].y, xv[m].x, z.y);
    }

    // S_hat = z / conj(tr) = z * tr / |tr|^2
    float inv2 = 1.0f / (tr.x * tr.x + tr.y * tr.y);
    float shr = (z.x * tr.x - z.y * tr.y) * inv2;
    float shi = (z.x * tr.y + z.y * tr.x) * inv2;

    // ---- 8. store (B,F,T,2) ----
    if (myCell < TOTAL) {
        int f  = myCell % FF;
        int bt = myCell / FF;
        int t  = bt % TT;
        int b  = bt / TT;
        float2* po = reinterpret_cast<float2*>(out);
        po[((size_t)b * FF + f) * TT + t] = make_float2(shr, shi);
    }
}

extern "C" void kernel_launch(void* const* d_in, const int* in_sizes, int n_in,
                              void* d_out, int out_size, void* d_ws, size_t ws_size,
                              hipStream_t stream) {
    const float* spec  = (const float*)d_in[0];
    const float* corrS = (const float*)d_in[1];
    const float* corrN = (const float*)d_in[2];
    float* out = (float*)d_out;

    mvdr_kernel<<<NCH, CELLS, 0, stream>>>(spec, corrS, corrN, out);
}